// Round 22
// baseline (121.131 us; speedup 1.0000x reference)
//
#include <hip/hip_runtime.h>

// ---------------------------------------------------------------------------
// AggMaskStarHead: SOLO-style dynamic mask head.
//
//  K0 k_pre     : fused gemm_ys | x0r | kin. v3: gemm branch batches 8
//                 channel loads per iteration (R21: 4x batching -10.4us;
//                 same mechanism, deeper MLP).
//  K6 k_cate    : 3x3 conv 256->80, OCB=8, 16-way ch split
//  K6b k_catnms : fused 16-way reduce + bias + sigmoid + points_nms
//  K1 k_mid     : HORIZONTAL FUSION of feat | kpconv (independent after
//                 catnms: feat writes B planes into CPP, kpconv writes KPP):
//                   blocks [0,2048)     = feat body (bf16 B-fragment planes)
//                   blocks [2048,2720)  = kpconv body (OCB=6, flattened grid)
//  K4b k_kpred  : sum partials + bias -> kpT[576][249]
//  K4c k_afrags : fused A1 + A2 bf16 hi/lo fragment emission
//  K8 k_dyn v13 : double-MFMA MLP, all-lane epilogue (frozen)
//
//  Order: pre -> cate -> catnms -> mid -> kpred -> afrags -> dyn.
// ---------------------------------------------------------------------------

// workspace float offsets
#define OFF_AHI   0u          // A1 hi: 147456 hw = 73728 floats (in Y0)
#define OFF_ALO   73728u      // A1 lo
#define OFF_A2HI  147456u     // A2 hi
#define OFF_A2LO  184320u     // A2 lo (ends 221184 < 262144 = Y0 size)
#define OFF_Y0   0u           // 16*16384
#define OFF_Y1   262144u      // 16*4096
#define OFF_Y2   327680u      // 16*1024
#define OFF_Y3   344064u      // 16*256
#define OFF_Y4   348160u      // 16*64
#define OFF_KIN  676864u      // 256*676  (26x26 zero-padded)
#define OFF_KPT  849920u      // 576*249
#define OFF_X0R  993344u      // 256*1764 (42x42 zero-padded)
#define OFF_KPP  1572928u     // 8*249*576 kpconv partials / cate slices 8..15
#define OFF_CPP  2720320u     // cate partial slices 0..7 (reused for B planes)
#define OFF_BHI  2720320u     // 524288 hw (inside CPP, post-catnms)
#define OFF_BLO  2982464u     // 524288 hw
// total 3744320 floats ~= 15 MB

#define SEG_ELEMS 9437184     // 576*128*128

typedef __attribute__((ext_vector_type(8))) short short8;
typedef __attribute__((ext_vector_type(4))) short short4v;
typedef __attribute__((ext_vector_type(4))) float f32x4;

__device__ __forceinline__ float sigmoidf_(float x) {
  return __builtin_amdgcn_rcpf(1.0f + __expf(-x));
}
__device__ __forceinline__ unsigned short f2bf(float f) {
  unsigned u = __float_as_uint(f);
  u += 0x7FFFu + ((u >> 16) & 1u);
  return (unsigned short)(u >> 16);
}
__device__ __forceinline__ float bf2f(unsigned short h) {
  return __uint_as_float(((unsigned)h) << 16);
}
__device__ __forceinline__ short4v i2_to_s4(int a, int b) {
  union { int i[2]; short4v s; } u;
  u.i[0] = a; u.i[1] = b;
  return u.s;
}
__device__ __forceinline__ f32x4 mfma16x16(short4v a, short4v b, f32x4 c) {
#if __has_builtin(__builtin_amdgcn_mfma_f32_16x16x16bf16_1k)
  return __builtin_amdgcn_mfma_f32_16x16x16bf16_1k(a, b, c, 0, 0, 0);
#else
  f32x4 d;
  asm volatile("v_mfma_f32_16x16x16_bf16 %0, %1, %2, %3"
               : "=v"(d) : "v"(a), "v"(b), "v"(c));
  return d;
#endif
}

// ---------------- K0 v3: fused gemm_ys | x0r | kin (8x batched gemm) -------
__global__ __launch_bounds__(256) void k_pre(
    const float* __restrict__ x0, const float* __restrict__ x1,
    const float* __restrict__ x2, const float* __restrict__ x3,
    const float* __restrict__ x4, const float* __restrict__ w_ctx,
    float* __restrict__ ws) {
  __shared__ float wl[2048];   // gemm branch only
  __shared__ float red[2048];
  const int bb_ = blockIdx.x, tid = threadIdx.x;
  if (bb_ < 682) {
    // ------------------ gemm_ys body, 8x batched loads ------------------
    const int b = bb_;
    int s, Q, qb;
    const float* xs;
    float* ys;
    if (b < 512)      { s = 0; xs = x0; ys = ws + OFF_Y0; Q = 16384; qb = (b >> 1) * 64; }
    else if (b < 640) { s = 1; xs = x1; ys = ws + OFF_Y1; Q = 4096;  qb = ((b - 512) >> 1) * 64; }
    else if (b < 672) { s = 2; xs = x2; ys = ws + OFF_Y2; Q = 1024;  qb = ((b - 640) >> 1) * 64; }
    else if (b < 680) { s = 3; xs = x3; ys = ws + OFF_Y3; Q = 256;   qb = ((b - 672) >> 1) * 64; }
    else              { s = 4; xs = x4; ys = ws + OFF_Y4; Q = 64;    qb = 0; }
    const int oh = (b & 1) * 8;
    for (int i = tid; i < 2048; i += 256) {
      const int c = i >> 3, o = i & 7;
      wl[i] = w_ctx[(oh + o) * 1280 + s * 256 + c];
    }
    __syncthreads();
    const int slice = tid >> 6, px = tid & 63;
    const int q = qb + px;
    float acc[8];
#pragma unroll
    for (int o = 0; o < 8; ++o) acc[o] = 0.f;
    const int c0 = slice * 64;
#pragma unroll 1
    for (int c = c0; c < c0 + 64; c += 8) {
      // 8 independent loads issued together (8x memory-level parallelism);
      // per-acc accumulation order unchanged (c ascending) -> bit-exact.
      float v[8];
#pragma unroll
      for (int u = 0; u < 8; ++u) v[u] = xs[(size_t)(c + u) * Q + q];
#pragma unroll
      for (int o = 0; o < 8; ++o) {
        float a = acc[o];
#pragma unroll
        for (int u = 0; u < 8; ++u) a = fmaf(wl[(c + u) * 8 + o], v[u], a);
        acc[o] = a;
      }
    }
#pragma unroll
    for (int o = 0; o < 8; ++o) red[slice * 512 + o * 64 + px] = acc[o];
    __syncthreads();
    const int og = tid >> 6, px2 = tid & 63;
#pragma unroll
    for (int j = 0; j < 2; ++j) {
      const int o = og * 2 + j;
      const float v = red[o * 64 + px2] + red[512 + o * 64 + px2] +
                      red[1024 + o * 64 + px2] + red[1536 + o * 64 + px2];
      ys[(oh + o) * Q + qb + px2] = v;
    }
  } else if (bb_ < 2446) {
    // ------------------ x0r body (unchanged) ------------------
    const int idx = (bb_ - 682) * 256 + tid;  // 256*1764
    float* xr = ws + OFF_X0R;
    const int c = idx / 1764, r = idx % 1764;
    const int py = r / 42, px = r % 42;
    const int oy = py - 1, ox = px - 1;
    if (oy < 0 || oy >= 40 || ox < 0 || ox >= 40) { xr[idx] = 0.f; return; }
    float wy[8], wx[8];
    int iy0, ix0;
    {
      const float s = (oy + 0.5f) * 3.2f - 0.5f;
      iy0 = (int)floorf(s) - 3;
      float sw = 0.f;
#pragma unroll
      for (int a = 0; a < 8; ++a) {
        const int i = iy0 + a;
        float w = fmaxf(1.0f - fabsf((float)i - s) * 0.3125f, 0.f);
        if (i < 0 || i > 127) w = 0.f;
        wy[a] = w; sw += w;
      }
      const float inv = __builtin_amdgcn_rcpf(sw);
#pragma unroll
      for (int a = 0; a < 8; ++a) wy[a] *= inv;
    }
    {
      const float s = (ox + 0.5f) * 3.2f - 0.5f;
      ix0 = (int)floorf(s) - 3;
      float sw = 0.f;
#pragma unroll
      for (int a = 0; a < 8; ++a) {
        const int i = ix0 + a;
        float w = fmaxf(1.0f - fabsf((float)i - s) * 0.3125f, 0.f);
        if (i < 0 || i > 127) w = 0.f;
        wx[a] = w; sw += w;
      }
      const float inv = __builtin_amdgcn_rcpf(sw);
#pragma unroll
      for (int a = 0; a < 8; ++a) wx[a] *= inv;
    }
    float acc = 0.f;
#pragma unroll
    for (int a = 0; a < 8; ++a) {
      const int iy = min(max(iy0 + a, 0), 127);
      const float* row = x0 + c * 16384 + iy * 128;
#pragma unroll
      for (int b2 = 0; b2 < 8; ++b2) {
        const int ix = min(max(ix0 + b2, 0), 127);
        acc = fmaf(wy[a] * wx[b2], row[ix], acc);
      }
    }
    xr[idx] = acc;
  } else {
    // ------------------ kin body (unchanged) ------------------
    const int idx = (bb_ - 2446) * 256 + tid;  // 256*676
    float* kin = ws + OFF_KIN;
    const int c = idx / 676, r = idx % 676;
    const int py = r / 26, px = r % 26;
    const int oy = py - 1, ox = px - 1;
    if (oy < 0 || oy >= 24 || ox < 0 || ox >= 24) { kin[idx] = 0.f; return; }
    float wy[4], wx[4];
    int iy0, ix0;
    {
      const float s = (oy + 0.5f) * (4.0f / 3.0f) - 0.5f;
      iy0 = (int)floorf(s) - 1;
      float sw = 0.f;
#pragma unroll
      for (int a = 0; a < 4; ++a) {
        const int i = iy0 + a;
        float w = fmaxf(1.0f - fabsf((float)i - s) * 0.75f, 0.f);
        if (i < 0 || i > 31) w = 0.f;
        wy[a] = w; sw += w;
      }
      const float inv = __builtin_amdgcn_rcpf(sw);
#pragma unroll
      for (int a = 0; a < 4; ++a) wy[a] *= inv;
    }
    {
      const float s = (ox + 0.5f) * (4.0f / 3.0f) - 0.5f;
      ix0 = (int)floorf(s) - 1;
      float sw = 0.f;
#pragma unroll
      for (int a = 0; a < 4; ++a) {
        const int i = ix0 + a;
        float w = fmaxf(1.0f - fabsf((float)i - s) * 0.75f, 0.f);
        if (i < 0 || i > 31) w = 0.f;
        wx[a] = w; sw += w;
      }
      const float inv = __builtin_amdgcn_rcpf(sw);
#pragma unroll
      for (int a = 0; a < 4; ++a) wx[a] *= inv;
    }
    float acc = 0.f;
#pragma unroll
    for (int a = 0; a < 4; ++a) {
      const int iy = min(max(iy0 + a, 0), 31);
      const float* row = x2 + c * 1024 + iy * 32;
#pragma unroll
      for (int b2 = 0; b2 < 4; ++b2) {
        const int ix = min(max(ix0 + b2, 0), 31);
        acc = fmaf(wy[a] * wx[b2], row[ix], acc);
      }
    }
    kin[idx] = acc;
  }
}

// ---------------- K1: fused feat | kpconv (both run after catnms) ----------
__global__ __launch_bounds__(256) void k_mid(
    const float* __restrict__ mask_feat, const float* __restrict__ b_ctx,
    const float* __restrict__ w_lw, float* __restrict__ ws) {
  const int bb_ = blockIdx.x, tid = threadIdx.x;
  if (bb_ < 2048) {
    // ------------------ feat body (unchanged) ------------------
    const int idx = bb_ * 256 + tid;  // 0..524287
    unsigned short* bhi = (unsigned short*)(ws + OFF_BHI);
    unsigned short* blo = (unsigned short*)(ws + OFF_BLO);
    int k, p;
    float v;
    if (idx < 65536) {
      k = idx >> 14;
      p = idx & 16383;
      v = mask_feat[idx];
    } else if (idx < 327680) {
      const int r = idx - 65536;
      const int o = r >> 14;
      p = r & 16383;
      k = 4 + o;
      const int y = p >> 7, x = p & 127;
      float acc = b_ctx[o] + ws[OFF_Y0 + o * 16384 + p];
      const unsigned offs[4] = {OFF_Y1, OFF_Y2, OFF_Y3, OFF_Y4};
      const int Ss[4] = {64, 32, 16, 8};
#pragma unroll
      for (int s = 0; s < 4; ++s) {
        const int S = Ss[s];
        const float sc = (float)S / 128.0f;
        const float fy = (y + 0.5f) * sc - 0.5f;
        const float fx = (x + 0.5f) * sc - 0.5f;
        const int iy = (int)floorf(fy), ix = (int)floorf(fx);
        const float ty = fy - (float)iy, tx = fx - (float)ix;
        const int y0 = iy < 0 ? 0 : iy;
        const int y1 = (iy + 1 > S - 1) ? S - 1 : iy + 1;
        const int x0 = ix < 0 ? 0 : ix;
        const int x1 = (ix + 1 > S - 1) ? S - 1 : ix + 1;
        const float* yb = ws + offs[s] + o * S * S;
        const float v00 = yb[y0 * S + x0], v01 = yb[y0 * S + x1];
        const float v10 = yb[y1 * S + x0], v11 = yb[y1 * S + x1];
        const float top = fmaf(tx, v01 - v00, v00);
        const float bot = fmaf(tx, v11 - v10, v10);
        acc += fmaf(ty, bot - top, top);
      }
      v = fmaxf(acc, 0.f);
    } else {
      const int r2 = idx - 327680;
      k = 20 + (r2 >> 14);
      p = r2 & 16383;
      v = (k == 20) ? 1.0f : 0.f;
    }
    const int t = p >> 4, col = p & 15, g = k >> 3, j = k & 7;
    const unsigned hw = ((unsigned)(t * 64 + col + 16 * g)) * 8u + (unsigned)j;
    const unsigned short hv = f2bf(v);
    bhi[hw] = hv;
    blo[hw] = f2bf(v - bf2f(hv));
  } else {
    // ------------------ kpconv body (flattened grid) ------------------
    const int bk = bb_ - 2048;          // [0, 672)
    const int og = bk >> 4;             // 42 groups
    const int r_ = bk & 15;
    const int sl = r_ >> 1;             // 8 slices
    const int z = r_ & 1;               // 2 px halves
    const int oc0 = og * 6;
    const float* kin = ws + OFF_KIN;
    const float* wbo[6];
#pragma unroll
    for (int o = 0; o < 6; ++o) {
      const int oc = min(oc0 + o, 248);
      wbo[o] = w_lw + (size_t)oc * 2304 + sl * 32 * 9;
    }
    float a[6][2];
#pragma unroll
    for (int o = 0; o < 6; ++o) { a[o][0] = 0.f; a[o][1] = 0.f; }
    const int pz = z * 288;
    const int p0 = pz + tid;
    const bool has1 = tid < 32;
    const int p1 = has1 ? p0 + 256 : p0;
    const int b0 = (p0 / 24) * 26 + (p0 % 24);
    const int b1 = (p1 / 24) * 26 + (p1 % 24);
    const float* kb = kin + sl * 32 * 676;
#pragma unroll 2
    for (int c = 0; c < 32; ++c) {
      const float* kc = kb + c * 676;
#pragma unroll
      for (int t = 0; t < 9; ++t) {
        const int d = (t / 3) * 26 + (t % 3);
        const float v0 = kc[b0 + d];
        const float v1 = kc[b1 + d];
#pragma unroll
        for (int o = 0; o < 6; ++o) {
          const float w = wbo[o][c * 9 + t];
          a[o][0] = fmaf(w, v0, a[o][0]);
          a[o][1] = fmaf(w, v1, a[o][1]);
        }
      }
    }
#pragma unroll
    for (int o = 0; o < 6; ++o) {
      if (oc0 + o < 249) {
        float* pp = ws + OFF_KPP + ((unsigned)(sl * 249 + oc0 + o)) * 576u;
        pp[p0] = a[o][0];
        if (has1) pp[p1] = a[o][1];
      }
    }
  }
}

// ---------------- K4b: reduce kpconv partials -> kpT[576][249] -------------
__global__ __launch_bounds__(256) void k_kpred(
    const float* __restrict__ b_lw, float* __restrict__ ws) {
  const int idx = blockIdx.x * 256 + threadIdx.x;
  if (idx >= 249 * 576) return;
  const int oc = idx / 576, p = idx % 576;
  const float* pp = ws + OFF_KPP;
  float s = b_lw[oc];
#pragma unroll
  for (int sl = 0; sl < 8; ++sl) s += pp[((unsigned)(sl * 249 + oc)) * 576u + p];
  int noc;
  if (oc < 160)      { noc = (oc % 20) * 8 + (oc / 20); }
  else if (oc < 168) { noc = oc; }
  else if (oc < 232) { const int t = oc - 168; noc = 168 + (t % 8) * 8 + (t / 8); }
  else               { noc = oc; }
  ws[OFF_KPT + (unsigned)p * 249u + noc] = s;
}

// ---------------- K4c: fused A1 + A2 fragment emission ---------------------
__global__ __launch_bounds__(256) void k_afrags(float* __restrict__ ws) {
  const int b = blockIdx.x;
  const float* kpTf = ws + OFF_KPT;
  if (b < 72) {
    const int gid = b * 256 + threadIdx.x;   // 18432 = 288 pairs * 64
    unsigned short* ahi = (unsigned short*)(ws + OFF_AHI);
    unsigned short* alo = (unsigned short*)(ws + OFF_ALO);
    const int P = gid >> 6, l = gid & 63;
    const int row = l & 15;
    const int pos = 2 * P + (row >> 3);
    const int d = row & 7;
    const int k0 = (l >> 4) * 8;
    short8 vh, vl;
#pragma unroll
    for (int j = 0; j < 8; ++j) {
      const int k = k0 + j;
      float v;
      if (k < 20)       v = kpTf[(size_t)pos * 249 + k * 8 + d];
      else if (k == 20) v = kpTf[(size_t)pos * 249 + 160 + d];
      else              v = 0.f;
      const unsigned short hv = f2bf(v);
      vh[j] = (short)hv;
      vl[j] = (short)f2bf(v - bf2f(hv));
    }
    *reinterpret_cast<short8*>(ahi + (size_t)gid * 8) = vh;
    *reinterpret_cast<short8*>(alo + (size_t)gid * 8) = vl;
  } else {
    const int gid = (b - 72) * 256 + threadIdx.x;  // 18432
    unsigned short* ahi = (unsigned short*)(ws + OFF_A2HI);
    unsigned short* alo = (unsigned short*)(ws + OFF_A2LO);
    const int P = gid >> 6, l = gid & 63;
    const int row = l & 15;
    const int pa = row >> 3, dp = row & 7;
    const int pos = 2 * P + pa;
    const int k0 = (l >> 4) * 4;
    short4v vh, vl;
#pragma unroll
    for (int j = 0; j < 4; ++j) {
      const int k = k0 + j;
      const float v =
          ((k >> 3) == pa) ? kpTf[(size_t)pos * 249 + 168 + (k & 7) * 8 + dp]
                           : 0.f;
      const unsigned short hv = f2bf(v);
      vh[j] = (short)hv;
      vl[j] = (short)f2bf(v - bf2f(hv));
    }
    *reinterpret_cast<short4v*>(ahi + (size_t)gid * 4) = vh;
    *reinterpret_cast<short4v*>(alo + (size_t)gid * 4) = vl;
  }
}

// ---------------- K6 v4: 3x3 conv 256->80, OCB=8 + px/4 + 16-way ch split --
__global__ __launch_bounds__(256) void k_cate(
    const float* __restrict__ w_cate, float* __restrict__ ws) {
  const int og = blockIdx.x, tid = threadIdx.x;
  const int pb = blockIdx.y * 400;
  const int sl = blockIdx.z;
  const int oc0 = og * 8;
  const float* xr = ws + OFF_X0R;
  const float* __restrict__ wb0 = w_cate + (size_t)oc0 * 2304 + sl * 16 * 9;
  float a[8][2];
#pragma unroll
  for (int o = 0; o < 8; ++o) { a[o][0] = 0.f; a[o][1] = 0.f; }
  const bool has1 = tid < 144;
  const int p0 = pb + tid;
  const int p1 = has1 ? p0 + 256 : p0;
  const int b0 = (p0 / 40) * 42 + (p0 % 40);
  const int b1 = (p1 / 40) * 42 + (p1 % 40);
  const float* xb0 = xr + sl * 16 * 1764;
#pragma unroll 2
  for (int c = 0; c < 16; ++c) {
    const float* xb = xb0 + c * 1764;
#pragma unroll
    for (int t = 0; t < 9; ++t) {
      const int d = (t / 3) * 42 + (t % 3);
      const float v0 = xb[b0 + d];
      const float v1 = xb[b1 + d];
#pragma unroll
      for (int o = 0; o < 8; ++o) {
        const float w = wb0[o * 2304 + c * 9 + t];
        a[o][0] = fmaf(w, v0, a[o][0]);
        a[o][1] = fmaf(w, v1, a[o][1]);
      }
    }
  }
  const unsigned base = (sl < 8)
      ? OFF_CPP + ((unsigned)(sl * 80 + oc0)) * 1600u
      : OFF_KPP + ((unsigned)((sl - 8) * 80 + oc0)) * 1600u;
#pragma unroll
  for (int o = 0; o < 8; ++o) {
    float* pp = ws + base + (unsigned)o * 1600u;
    pp[p0] = a[o][0];
    if (has1) pp[p1] = a[o][1];
  }
}

// ---------------- K6b: fused 16-way reduce + bias + sigmoid + nms ----------
__global__ __launch_bounds__(256) void k_catnms(
    const float* __restrict__ b_cate, const float* __restrict__ ws,
    float* __restrict__ out) {
  __shared__ float sm[1600];
  const int oc = blockIdx.x, tid = threadIdx.x;
  const float b = b_cate[oc];
  for (int px = tid; px < 1600; px += 256) {
    float s = b;
#pragma unroll
    for (int sl = 0; sl < 8; ++sl)
      s += ws[OFF_CPP + ((unsigned)(sl * 80 + oc)) * 1600u + px];
#pragma unroll
    for (int sl = 0; sl < 8; ++sl)
      s += ws[OFF_KPP + ((unsigned)(sl * 80 + oc)) * 1600u + px];
    sm[px] = sigmoidf_(s);
  }
  __syncthreads();
  for (int px = tid; px < 1600; px += 256) {
    const int y = px / 40, x = px % 40;
    const float v = sm[px];
    float m = v;
    if (y > 0 && x > 0) m = fmaxf(m, sm[px - 41]);
    if (y > 0)          m = fmaxf(m, sm[px - 40]);
    if (x > 0)          m = fmaxf(m, sm[px - 1]);
    out[SEG_ELEMS + oc * 1600 + px] = (m == v) ? v : 0.f;
  }
}

// ---------------- K8 v13: double-MFMA MLP, all-lane epilogue ---------------
#define DYN_POS 12
#define DYN_PAIRS 6
__global__ __launch_bounds__(256, 4) void k_dyn(
    const float* __restrict__ ws, float* __restrict__ out) {
  __shared__ __align__(16) short a1h_l[DYN_PAIRS * 64 * 8];  // 6 KB
  __shared__ __align__(16) short a1l_l[DYN_PAIRS * 64 * 8];  // 6 KB
  __shared__ __align__(16) short a2h_l[DYN_PAIRS * 64 * 4];  // 3 KB
  __shared__ __align__(16) short a2l_l[DYN_PAIRS * 64 * 4];  // 3 KB
  __shared__ __align__(16) float lw3[DYN_POS * 20];          // 960 B
  const int tid = threadIdx.x;
  const float* kpTf = ws + OFF_KPT;
  const unsigned short* bhip = (const unsigned short*)(ws + OFF_BHI);
  const unsigned short* blop = (const unsigned short*)(ws + OFF_BLO);
  const int n0 = blockIdx.y * DYN_POS;
  const int P0 = blockIdx.y * DYN_PAIRS;
  {
    const unsigned* s1h = (const unsigned*)((const unsigned short*)(ws + OFF_AHI) + (size_t)P0 * 512);
    const unsigned* s1l = (const unsigned*)((const unsigned short*)(ws + OFF_ALO) + (size_t)P0 * 512);
    const unsigned* s2h = (const unsigned*)((const unsigned short*)(ws + OFF_A2HI) + (size_t)P0 * 256);
    const unsigned* s2l = (const unsigned*)((const unsigned short*)(ws + OFF_A2LO) + (size_t)P0 * 256);
    unsigned* d1h = (unsigned*)a1h_l;
    unsigned* d1l = (unsigned*)a1l_l;
    unsigned* d2h = (unsigned*)a2h_l;
    unsigned* d2l = (unsigned*)a2l_l;
#pragma unroll
    for (int i = 0; i < 6; ++i) d1h[tid + i * 256] = s1h[tid + i * 256];
#pragma unroll
    for (int i = 0; i < 6; ++i) d1l[tid + i * 256] = s1l[tid + i * 256];
#pragma unroll
    for (int i = 0; i < 3; ++i) d2h[tid + i * 256] = s2h[tid + i * 256];
#pragma unroll
    for (int i = 0; i < 3; ++i) d2l[tid + i * 256] = s2l[tid + i * 256];
  }
  if (tid < DYN_POS * 20) {
    const int p = tid / 20, j = tid - p * 20;
    float v = 0.f;
    if (j < 8)        v = kpTf[(size_t)(n0 + p) * 249 + 232 + j];           // b1
    else if (j < 16)  v = kpTf[(size_t)(n0 + p) * 249 + 240 + (j - 8)];     // w2
    else if (j == 16) v = kpTf[(size_t)(n0 + p) * 249 + 248];               // b2
    lw3[tid] = v;
  }
  __syncthreads();
  const int wv = tid >> 6, l = tid & 63;
  const int t0 = blockIdx.x * 8 + wv * 2;      // first of 2 tiles
  const int c16 = l & 15;
  const int g = l >> 4;
  const int pa = g >> 1;
  const int tsel = g & 1;                      // which tile this lane stores
  const int pxw = t0 * 16 + c16 + tsel * 16;   // write pixel
  const float* b1base = &lw3[pa * 20 + (g & 1) * 4];
  const float* w2base = &lw3[pa * 20 + 8 + (g & 1) * 4];
  const short8 bh0 = *reinterpret_cast<const short8*>(bhip + ((size_t)t0 * 64 + l) * 8);
  const short8 bl0 = *reinterpret_cast<const short8*>(blop + ((size_t)t0 * 64 + l) * 8);
  const short8 bh1 = *reinterpret_cast<const short8*>(bhip + ((size_t)(t0 + 1) * 64 + l) * 8);
  const short8 bl1 = *reinterpret_cast<const short8*>(blop + ((size_t)(t0 + 1) * 64 + l) * 8);
#pragma unroll 2
  for (int q = 0; q < DYN_PAIRS; ++q) {
    const int P = P0 + q;
    const short8 a1h = *reinterpret_cast<const short8*>(&a1h_l[(q * 64 + l) * 8]);
    const short8 a1l = *reinterpret_cast<const short8*>(&a1l_l[(q * 64 + l) * 8]);
    const short4v a2h = *reinterpret_cast<const short4v*>(&a2h_l[(q * 64 + l) * 4]);
    const short4v a2l = *reinterpret_cast<const short4v*>(&a2l_l[(q * 64 + l) * 4]);
    const float4 b1v = *reinterpret_cast<const float4*>(b1base + q * 40);
    const float4 w2v = *reinterpret_cast<const float4*>(w2base + q * 40);
    const float b2s = lw3[(q * 2 + pa) * 20 + 16];
    float s0, s1;
    // ---- tile 0 partial dot ----
    {
      f32x4 c1 = {0.f, 0.f, 0.f, 0.f};
      c1 = __builtin_amdgcn_mfma_f32_16x16x32_bf16(a1h, bh0, c1, 0, 0, 0);
      c1 = __builtin_amdgcn_mfma_f32_16x16x32_bf16(a1h, bl0, c1, 0, 0, 0);
      c1 = __builtin_amdgcn_mfma_f32_16x16x32_bf16(a1l, bh0, c1, 0, 0, 0);
      const float v0 = fmaxf(c1[0], 0.f);
      const float v1 = fmaxf(c1[1], 0.f);
      const float v2 = fmaxf(c1[2], 0.f);
      const float v3 = fmaxf(c1[3], 0.f);
      const unsigned u0 = __float_as_uint(v0), u1 = __float_as_uint(v1);
      const unsigned u2 = __float_as_uint(v2), u3 = __float_as_uint(v3);
      const int bhD0 = (int)((u1 & 0xFFFF0000u) | (u0 >> 16));
      const int bhD1 = (int)((u3 & 0xFFFF0000u) | (u2 >> 16));
      const short4v b2h = i2_to_s4(bhD0, bhD1);
      f32x4 c2 = {b1v.x, b1v.y, b1v.z, b1v.w};
      c2 = mfma16x16(a2h, b2h, c2);
      c2 = mfma16x16(a2l, b2h, c2);
      float s = w2v.x * fmaxf(c2[0], 0.f);
      s = fmaf(w2v.y, fmaxf(c2[1], 0.f), s);
      s = fmaf(w2v.z, fmaxf(c2[2], 0.f), s);
      s = fmaf(w2v.w, fmaxf(c2[3], 0.f), s);
      s0 = s;
    }
    // ---- tile 1 partial dot ----
    {
      f32x4 c1 = {0.f, 0.f, 0.f, 0.f};
      c1 = __builtin_amdgcn_mfma_f32_16x16x32_bf16(a1h, bh1, c1, 0, 0, 0);
      c1 = __builtin_amdgcn_mfma_f32_16x16x32_bf16(a1h, bl1, c1, 0, 0, 0);
      c1 = __builtin_amdgcn_mfma_f32_16x16x32_bf16(a1l, bh1, c1, 0, 0, 0);
      const float v0 = fmaxf(c1[0], 0.f);
      const float v1 = fmaxf(c1[1], 0.f);
      const float v2 = fmaxf(c1[2], 0.f);
      const float v3 = fmaxf(c1[3], 0.f);
      const unsigned u0 = __float_as_uint(v0), u1 = __float_as_uint(v1);
      const unsigned u2 = __float_as_uint(v2), u3 = __float_as_uint(v3);
      const int bhD0 = (int)((u1 & 0xFFFF0000u) | (u0 >> 16));
      const int bhD1 = (int)((u3 & 0xFFFF0000u) | (u2 >> 16));
      const short4v b2h = i2_to_s4(bhD0, bhD1);
      f32x4 c2 = {b1v.x, b1v.y, b1v.z, b1v.w};
      c2 = mfma16x16(a2h, b2h, c2);
      c2 = mfma16x16(a2l, b2h, c2);
      float s = w2v.x * fmaxf(c2[0], 0.f);
      s = fmaf(w2v.y, fmaxf(c2[1], 0.f), s);
      s = fmaf(w2v.z, fmaxf(c2[2], 0.f), s);
      s = fmaf(w2v.w, fmaxf(c2[3], 0.f), s);
      s1 = s;
    }
    // ---- all-lane epilogue: fold both, select by tile parity, 1 store ----
    const float f0 = s0 + __shfl_xor(s0, 16);
    const float f1 = s1 + __shfl_xor(s1, 16);
    const float m = (tsel ? f1 : f0) + b2s;
    out[(size_t)(2 * P + pa) * 16384 + pxw] = sigmoidf_(m);
  }
}

// ---------------------------------------------------------------------------
extern "C" void kernel_launch(void* const* d_in, const int* in_sizes, int n_in,
                              void* d_out, int out_size, void* d_ws, size_t ws_size,
                              hipStream_t stream) {
  const float* x0        = (const float*)d_in[0];
  const float* x1        = (const float*)d_in[1];
  const float* x2        = (const float*)d_in[2];
  const float* x3        = (const float*)d_in[3];
  const float* x4        = (const float*)d_in[4];
  const float* mask_feat = (const float*)d_in[5];
  const float* w_ctx     = (const float*)d_in[6];
  const float* b_ctx     = (const float*)d_in[7];
  const float* w_lw      = (const float*)d_in[8];
  const float* b_lw      = (const float*)d_in[9];
  const float* w_cate    = (const float*)d_in[10];
  const float* b_cate    = (const float*)d_in[11];
  float* out = (float*)d_out;
  float* ws  = (float*)d_ws;

  // Order: pre -> cate -> catnms (consumes CPP+KPP cate partials) ->
  // mid (feat|kpconv fused; feat writes B planes into CPP, kpconv into KPP)
  // -> kpred -> afrags -> dyn.
  hipLaunchKernelGGL(k_pre, dim3(3122), dim3(256), 0, stream,
                     x0, x1, x2, x3, x4, w_ctx, ws);
  hipLaunchKernelGGL(k_cate, dim3(10, 4, 16), dim3(256), 0, stream,
                     w_cate, ws);
  hipLaunchKernelGGL(k_catnms, dim3(80), dim3(256), 0, stream,
                     b_cate, ws, out);
  hipLaunchKernelGGL(k_mid, dim3(2720), dim3(256), 0, stream,
                     mask_feat, b_ctx, w_lw, ws);
  hipLaunchKernelGGL(k_kpred, dim3(561), dim3(256), 0, stream, b_lw, ws);
  hipLaunchKernelGGL(k_afrags, dim3(144), dim3(256), 0, stream, ws);
  hipLaunchKernelGGL(k_dyn, dim3(128, 48), dim3(256), 0, stream, ws, out);
}